// Round 5
// baseline (369.868 us; speedup 1.0000x reference)
//
#include <hip/hip_runtime.h>
#include <math.h>

#define B_    2048
#define T_    8
#define CIN_  2048
#define CH_   1024
#define M_    32
#define NCLS_ 21
#define NM_   (NCLS_*M_)   // 672
#define NMP_  768          // nm padded to 6*128
#define EPS_  1e-8f
#define ZKV_  4            // split-K planes for fused kv+E GEMM
#define ZC_   2            // split-K planes for cos GEMM

typedef __bf16 bf16_t;
typedef bf16_t bf16x4 __attribute__((ext_vector_type(4)));
typedef bf16_t bf16x8 __attribute__((ext_vector_type(8)));
typedef float  floatx4 __attribute__((ext_vector_type(4)));

#define GLOBAL_AS __attribute__((address_space(1)))
#define LDS_AS    __attribute__((address_space(3)))

// ---------------------------------------------------------------------------
// 128x128 bf16 MFMA GEMM, split-K over blockIdx.z:
//   C[z][M][N] partial = A[., zK..zK+Ksplit) . B^T (+ bias if z==0)
//   m0 >= msplit switches operand set (A1,B1,bias1). Rows >= mzero -> 0.
// ---------------------------------------------------------------------------
__global__ __launch_bounds__(256) void gemm128(
    const bf16_t* __restrict__ A0, const bf16_t* __restrict__ A1, int msplit,
    const bf16_t* __restrict__ B0, const bf16_t* __restrict__ B1,
    const float* __restrict__ bias0, const float* __restrict__ bias1,
    int ld, float* __restrict__ C, int ldc, size_t strideC, int mzero, int Ksplit)
{
  __shared__ bf16_t As[128 * 64];
  __shared__ bf16_t Bs[128 * 64];
  const int tid = threadIdx.x;
  const int n0 = blockIdx.x * 128, m0 = blockIdx.y * 128;
  const int z = blockIdx.z;

  const bf16_t* A; const bf16_t* B; const float* bias; int mrow;
  if (m0 < msplit) { A = A0; B = B0; bias = bias0; mrow = m0; }
  else             { A = A1; B = B1; bias = bias1; mrow = m0 - msplit; }
  const int koff = z * Ksplit;

  const int w = tid >> 6, lane = tid & 63;
  const int srow = lane >> 3;
  const int sblk = (lane & 7) ^ srow;   // xor-swizzle folded into global addr
  const bf16_t* ga = A + (size_t)(mrow + w * 32 + srow) * ld + koff + sblk * 8;
  const bf16_t* gb = B + (size_t)(n0   + w * 32 + srow) * ld + koff + sblk * 8;

  const int wm = (w >> 1) * 64, wn = (w & 1) * 64;
  const int l15 = lane & 15, quad = lane >> 4;
  const int sx = l15 & 7;

  floatx4 acc[4][4] = {};

  for (int k0 = 0; k0 < Ksplit; k0 += 64) {
    __syncthreads();
    #pragma unroll
    for (int q = 0; q < 4; ++q) {
      __builtin_amdgcn_global_load_lds(
          (const GLOBAL_AS void*)(ga + (size_t)q * 8 * ld),
          (LDS_AS void*)(&As[(w * 4 + q) * 512]), 16, 0, 0);
      __builtin_amdgcn_global_load_lds(
          (const GLOBAL_AS void*)(gb + (size_t)q * 8 * ld),
          (LDS_AS void*)(&Bs[(w * 4 + q) * 512]), 16, 0, 0);
    }
    ga += 64; gb += 64;
    __syncthreads();
    #pragma unroll
    for (int ks = 0; ks < 2; ++ks) {
      bf16x8 af[4], bfr[4];
      #pragma unroll
      for (int i = 0; i < 4; ++i)
        af[i] = *(const bf16x8*)(&As[(wm + i * 16 + l15) * 64 + ((ks * 4 + quad) ^ sx) * 8]);
      #pragma unroll
      for (int j = 0; j < 4; ++j)
        bfr[j] = *(const bf16x8*)(&Bs[(wn + j * 16 + l15) * 64 + ((ks * 4 + quad) ^ sx) * 8]);
      #pragma unroll
      for (int i = 0; i < 4; ++i)
        #pragma unroll
        for (int j = 0; j < 4; ++j)
          acc[i][j] = __builtin_amdgcn_mfma_f32_16x16x32_bf16(af[i], bfr[j], acc[i][j], 0, 0, 0);
    }
  }

  float* Cz = C + (size_t)z * strideC;
  #pragma unroll
  for (int i = 0; i < 4; ++i) {
    const int rbase = m0 + wm + i * 16 + quad * 4;
    #pragma unroll
    for (int j = 0; j < 4; ++j) {
      const int c = n0 + wn + j * 16 + l15;
      const float badd = (bias && z == 0) ? bias[c] : 0.f;
      #pragma unroll
      for (int r = 0; r < 4; ++r) {
        const int rr = rbase + r;
        float v = acc[i][j][r] + badd;
        if (rr >= mzero) v = 0.f;
        Cz[(size_t)rr * ldc + c] = v;
      }
    }
  }
}

// ---------------------------------------------------------------------------
// 128x64 bf16 MFMA GEMM, split-K over z. MODE 0: f32 partials to C+z*strideC.
// MODE 1: bf16 relu store to Cb (single z). Each wave: 32(M)x64(N).
// ---------------------------------------------------------------------------
template<int MODE>
__global__ __launch_bounds__(256) void gemm_n64(
    const bf16_t* __restrict__ A, const bf16_t* __restrict__ B, int ld,
    float* __restrict__ C, bf16_t* __restrict__ Cb, int ldc, size_t strideC,
    int Ksplit)
{
  __shared__ bf16_t As[128 * 64];
  __shared__ bf16_t Bs[64 * 64];
  const int tid = threadIdx.x;
  const int n0 = blockIdx.x * 64, m0 = blockIdx.y * 128;
  const int z = blockIdx.z;
  const int koff = z * Ksplit;

  const int w = tid >> 6, lane = tid & 63;
  const int srow = lane >> 3;
  const int sblk = (lane & 7) ^ srow;
  const bf16_t* ga = A + (size_t)(m0 + w * 32 + srow) * ld + koff + sblk * 8;
  const bf16_t* gb = B + (size_t)(n0 + w * 16 + srow) * ld + koff + sblk * 8;

  const int l15 = lane & 15, quad = lane >> 4;
  const int sx = l15 & 7;

  floatx4 acc[2][4] = {};

  for (int k0 = 0; k0 < Ksplit; k0 += 64) {
    __syncthreads();
    #pragma unroll
    for (int q = 0; q < 4; ++q)
      __builtin_amdgcn_global_load_lds(
          (const GLOBAL_AS void*)(ga + (size_t)q * 8 * ld),
          (LDS_AS void*)(&As[(w * 4 + q) * 512]), 16, 0, 0);
    #pragma unroll
    for (int q = 0; q < 2; ++q)
      __builtin_amdgcn_global_load_lds(
          (const GLOBAL_AS void*)(gb + (size_t)q * 8 * ld),
          (LDS_AS void*)(&Bs[(w * 2 + q) * 512]), 16, 0, 0);
    ga += 64; gb += 64;
    __syncthreads();
    #pragma unroll
    for (int ks = 0; ks < 2; ++ks) {
      bf16x8 af[2], bfr[4];
      #pragma unroll
      for (int i = 0; i < 2; ++i)
        af[i] = *(const bf16x8*)(&As[(w * 32 + i * 16 + l15) * 64 + ((ks * 4 + quad) ^ sx) * 8]);
      #pragma unroll
      for (int j = 0; j < 4; ++j)
        bfr[j] = *(const bf16x8*)(&Bs[(j * 16 + l15) * 64 + ((ks * 4 + quad) ^ sx) * 8]);
      #pragma unroll
      for (int i = 0; i < 2; ++i)
        #pragma unroll
        for (int j = 0; j < 4; ++j)
          acc[i][j] = __builtin_amdgcn_mfma_f32_16x16x32_bf16(af[i], bfr[j], acc[i][j], 0, 0, 0);
    }
  }

  #pragma unroll
  for (int i = 0; i < 2; ++i) {
    const int rbase = m0 + w * 32 + i * 16 + quad * 4;
    #pragma unroll
    for (int j = 0; j < 4; ++j) {
      const int c = n0 + j * 16 + l15;
      #pragma unroll
      for (int r = 0; r < 4; ++r) {
        const int rr = rbase + r;
        if (MODE == 0)
          (C + (size_t)z * strideC)[(size_t)rr * ldc + c] = acc[i][j][r];
        else
          Cb[(size_t)rr * ldc + c] = (bf16_t)fmaxf(acc[i][j][r], 0.f);
      }
    }
  }
}

// ---------------------------------------------------------------------------
// Merged prep: f32->bf16 of x-slice / [Wk;Wv] / [WEk;WEv] / Wout, bias
// concat, and sf transpose. grid 4620 x 256.
//   blk 0..3071   : big conversions (sec = blk>>10)
//   blk 3072      : biases
//   blk 3073..3083: Wout -> bf16
//   blk 3084..4619: sf[n][c][m] -> sfTb[n*32+m][c] (pad rows zero)
// ---------------------------------------------------------------------------
__global__ __launch_bounds__(256) void kPrepAll(
    const float* __restrict__ x, const float* __restrict__ Wk,
    const float* __restrict__ Wv, const float* __restrict__ WEk,
    const float* __restrict__ WEv, const float* __restrict__ bk,
    const float* __restrict__ bv, const float* __restrict__ bEk,
    const float* __restrict__ bEv, const float* __restrict__ Wout,
    const float* __restrict__ sf,
    bf16_t* __restrict__ xb, bf16_t* __restrict__ Wkvb, bf16_t* __restrict__ WEb,
    bf16_t* __restrict__ Woutb, bf16_t* __restrict__ sfTb,
    float* __restrict__ bkv, float* __restrict__ bE)
{
  __shared__ float t[32][33];
  const int blk = blockIdx.x;
  const int tid = threadIdx.x;

  if (blk >= 3084) {   // sf transpose
    const int tt = blk - 3084;        // 0..1535
    const int nn = tt % 24;
    const int c0 = (tt / 24) * 32;
    const int cc = tid & 31, r8 = tid >> 5;
    #pragma unroll
    for (int q = 0; q < 4; ++q) {
      const int cl = r8 + q * 8;
      float v = 0.f;
      if (nn < NCLS_) v = sf[((size_t)nn * CIN_ + c0 + cl) * M_ + cc];
      t[cl][cc] = v;
    }
    __syncthreads();
    #pragma unroll
    for (int q = 0; q < 4; ++q) {
      const int ml = r8 + q * 8;
      sfTb[(size_t)(nn * 32 + ml) * CIN_ + c0 + cc] = (bf16_t)t[cc][ml];
    }
    return;
  }
  if (blk == 3072) {
    for (int i = tid; i < CH_; i += 256) {
      bkv[i] = bk[i]; bkv[CH_ + i] = bv[i];
      bE[i]  = bEk[i]; bE[CH_ + i] = bEv[i];
    }
    return;
  }
  if (blk > 3072) {    // Wout
    const size_t e0 = ((size_t)(blk - 3073) * 256 + tid) * 16;
    if (e0 < (size_t)NCLS_ * 2 * CH_) {
      #pragma unroll
      for (int q = 0; q < 4; ++q) {
        const float4 v = *(const float4*)(Wout + e0 + q * 4);
        bf16x4 o = { (bf16_t)v.x, (bf16_t)v.y, (bf16_t)v.z, (bf16_t)v.w };
        *(bf16x4*)(Woutb + e0 + q * 4) = o;
      }
    }
    return;
  }
  const int sec = blk >> 10;
  const int tt = ((blk & 1023) << 8) + tid;
  const size_t e0 = (size_t)tt * 16;
  const int row = (int)(e0 >> 11);
  const int col = (int)(e0 & 2047);
  const float* src;
  bf16_t* dst;
  if (sec == 0) {
    src = x + (size_t)row * (T_ * CIN_) + (size_t)(T_ - 1) * CIN_ + col;
    dst = xb + e0;
  } else if (sec == 1) {
    src = (row < CH_ ? Wk + (size_t)row * CIN_ : Wv + (size_t)(row - CH_) * CIN_) + col;
    dst = Wkvb + e0;
  } else {
    src = (row < CH_ ? WEk + (size_t)row * CIN_ : WEv + (size_t)(row - CH_) * CIN_) + col;
    dst = WEb + e0;
  }
  #pragma unroll
  for (int q = 0; q < 4; ++q) {
    const float4 v = *(const float4*)(src + q * 4);
    bf16x4 o = { (bf16_t)v.x, (bf16_t)v.y, (bf16_t)v.z, (bf16_t)v.w };
    *(bf16x4*)(dst + q * 4) = o;
  }
}

// ---------------------------------------------------------------------------
// Merged norm + Ev transpose (KVE = sum of ZKV_ planes, stride PS):
//   blk 0..703   : 4 rows each (wave per row). Normalize cols 0..1023 of row
//                  r -> knb (r<2048) or Eknb; r>=2048 also EvW = dot(Ev, Ww).
//   blk 704..1471: Ev2b[o][nm] = sum_z KVE_z[2048+nm][1024+o] (bf16), 32x32.
// grid 1472 x 256.
// ---------------------------------------------------------------------------
__global__ __launch_bounds__(256) void kNormTr(
    const float* __restrict__ KVE, size_t PS, const float* __restrict__ Ww,
    bf16_t* __restrict__ knb, bf16_t* __restrict__ Eknb, float* __restrict__ EvW,
    bf16_t* __restrict__ Ev2b)
{
  __shared__ float t[32][33];
  const int blk = blockIdx.x;
  const int tid = threadIdx.x;

  if (blk < 704) {
    const int r = blk * 4 + (tid >> 6);
    const int lane = tid & 63;
    const float* row = KVE + (size_t)r * 2048;
    float vals[16];
    float ss = 0.f;
    #pragma unroll
    for (int i = 0; i < 16; ++i) {
      const int o = lane + i * 64;
      float v = row[o];
      #pragma unroll
      for (int z = 1; z < ZKV_; ++z) v += row[(size_t)z * PS + o];
      vals[i] = v;
      ss += v * v;
    }
    for (int off = 32; off; off >>= 1) ss += __shfl_xor(ss, off);
    const float inv = 1.f / fmaxf(sqrtf(ss), EPS_);
    bf16_t* dst = (r < B_) ? knb + (size_t)r * CH_ : Eknb + (size_t)(r - B_) * CH_;
    #pragma unroll
    for (int i = 0; i < 16; ++i) dst[lane + i * 64] = (bf16_t)(vals[i] * inv);
    if (r >= B_) {
      float dd = 0.f;
      for (int o = lane; o < CH_; o += 64) {
        float v = row[CH_ + o];
        #pragma unroll
        for (int z = 1; z < ZKV_; ++z) v += row[(size_t)z * PS + CH_ + o];
        dd += v * Ww[o];
      }
      for (int off = 32; off; off >>= 1) dd += __shfl_xor(dd, off);
      if (lane == 0) EvW[r - B_] = dd;
    }
    return;
  }
  const int tt = blk - 704;           // 0..767
  const int nm0 = (tt % 24) * 32;
  const int o0 = (tt / 24) * 32;
  const int cc = tid & 31, r8 = tid >> 5;
  #pragma unroll
  for (int q = 0; q < 4; ++q) {
    const int r = r8 + q * 8;
    const size_t idx = (size_t)(B_ + nm0 + r) * 2048 + CH_ + o0 + cc;
    float v = KVE[idx];
    #pragma unroll
    for (int z = 1; z < ZKV_; ++z) v += KVE[(size_t)z * PS + idx];
    t[r][cc] = v;
  }
  __syncthreads();
  #pragma unroll
  for (int q = 0; q < 4; ++q) {
    const int r = r8 + q * 8;
    Ev2b[(size_t)(o0 + r) * NMP_ + nm0 + cc] = (bf16_t)t[cc][r];
  }
}

// ---------------------------------------------------------------------------
// Softmax chain per b, summing ZC_ cos planes (stride PSc). -> wwb bf16.
// ---------------------------------------------------------------------------
__global__ __launch_bounds__(256) void kSoftmax(
    const float* __restrict__ cosb, size_t PSc,
    const float* __restrict__ EvW, const float* __restrict__ bw,
    bf16_t* __restrict__ wwb)
{
  const int b = blockIdx.x;
  const int tid = threadIdx.x;
  __shared__ float sc[NM_];
  __shared__ float sl[NCLS_];
  for (int i = tid; i < NM_; i += 256) {
    float v = cosb[(size_t)b * NMP_ + i];
    #pragma unroll
    for (int z = 1; z < ZC_; ++z) v += cosb[(size_t)z * PSc + (size_t)b * NMP_ + i];
    sc[i] = v;
  }
  __syncthreads();
  if (tid < NCLS_) {
    const int base = tid * M_;
    float mx = -1e30f;
    for (int m = 0; m < M_; ++m) mx = fmaxf(mx, sc[base + m]);
    float s = 0.f;
    for (int m = 0; m < M_; ++m) {
      const float e = __expf(sc[base + m] - mx);
      sc[base + m] = e;
      s += e;
    }
    const float inv = 1.f / s;
    float lg = 0.f;
    for (int m = 0; m < M_; ++m) {
      const float w = sc[base + m] * inv;
      sc[base + m] = w;
      lg += w * EvW[base + m];
    }
    sl[tid] = lg + bw[0];
  }
  __syncthreads();
  if (tid == 0) {
    float mx = -1e30f;
    for (int n = 0; n < NCLS_; ++n) mx = fmaxf(mx, sl[n]);
    float s = 0.f;
    for (int n = 0; n < NCLS_; ++n) { const float e = __expf(sl[n] - mx); sl[n] = e; s += e; }
    const float inv = 1.f / s;
    for (int n = 0; n < NCLS_; ++n) sl[n] *= inv;
  }
  __syncthreads();
  for (int i = tid; i < NMP_; i += 256) {
    const float v = (i < NM_) ? sc[i] * sl[i >> 5] : 0.f;
    wwb[(size_t)b * NMP_ + i] = (bf16_t)v;
  }
}

// ---------------------------------------------------------------------------
// out[b,n] = bout[n] + sum_j relu(h[j]) * Woutb[n,j]; h = [sum_z v_z, fEb]
// ---------------------------------------------------------------------------
__global__ __launch_bounds__(256) void kOut(
    const float* __restrict__ KVE, size_t PS,
    const bf16_t* __restrict__ fEb, const bf16_t* __restrict__ Woutb,
    const float* __restrict__ bout, float* __restrict__ out)
{
  const int b = blockIdx.x;
  const int tid = threadIdx.x;
  __shared__ float h[2 * CH_];
  for (int j = tid; j < CH_; j += 256) {
    const size_t idx = (size_t)b * 2048 + CH_ + j;
    float v = KVE[idx];
    #pragma unroll
    for (int z = 1; z < ZKV_; ++z) v += KVE[(size_t)z * PS + idx];
    h[j] = fmaxf(v, 0.f);
  }
  for (int j = tid; j < CH_; j += 256)
    h[CH_ + j] = (float)fEb[(size_t)b * CH_ + j];
  __syncthreads();
  const int wave = tid >> 6, lane = tid & 63;
  for (int n = wave; n < NCLS_; n += 4) {
    const bf16_t* wr = Woutb + (size_t)n * (2 * CH_);
    float s = 0.f;
    for (int j = lane; j < 2 * CH_; j += 64) s += h[j] * (float)wr[j];
    for (int off = 32; off; off >>= 1) s += __shfl_xor(s, off);
    if (lane == 0) out[(size_t)b * NCLS_ + n] = s + bout[n];
  }
}

// ---------------------------------------------------------------------------
extern "C" void kernel_launch(void* const* d_in, const int* in_sizes, int n_in,
                              void* d_out, int out_size, void* d_ws, size_t ws_size,
                              hipStream_t stream)
{
  const float* x    = (const float*)d_in[0];
  const float* sf   = (const float*)d_in[1];
  const float* Wk   = (const float*)d_in[2];
  const float* bk   = (const float*)d_in[3];
  const float* Wv   = (const float*)d_in[4];
  const float* bv   = (const float*)d_in[5];
  const float* WEk  = (const float*)d_in[6];
  const float* bEk  = (const float*)d_in[7];
  const float* WEv  = (const float*)d_in[8];
  const float* bEv  = (const float*)d_in[9];
  const float* Ww   = (const float*)d_in[10];
  const float* bw   = (const float*)d_in[11];
  const float* Wout = (const float*)d_in[12];
  const float* bout = (const float*)d_in[13];
  float* out = (float*)d_out;

  char* ws = (char*)d_ws;
  size_t off = 0;
  auto alloc = [&](size_t bytes) { char* p = ws + off; off += (bytes + 255) & ~(size_t)255; return p; };
  const size_t PS  = (size_t)2816 * 2048;               // KVE plane elems
  const size_t PSc = (size_t)B_ * NMP_;                 // cos plane elems
  float*  KVE   = (float*)alloc(PS * ZKV_ * 4);         // 92.3 MB
  bf16_t* xb    = (bf16_t*)alloc((size_t)2048 * 2048 * 2);
  bf16_t* Wkvb  = (bf16_t*)alloc((size_t)2048 * 2048 * 2);
  bf16_t* WEb   = (bf16_t*)alloc((size_t)2048 * 2048 * 2);
  bf16_t* sfTb  = (bf16_t*)alloc((size_t)NMP_ * 2048 * 2);
  bf16_t* knb   = (bf16_t*)alloc((size_t)B_ * CH_ * 2);
  bf16_t* Eknb  = (bf16_t*)alloc((size_t)NMP_ * CH_ * 2);
  bf16_t* Ev2b  = (bf16_t*)alloc((size_t)CH_ * NMP_ * 2);
  float*  cosb  = (float*)alloc(PSc * ZC_ * 4);
  bf16_t* wwb   = (bf16_t*)alloc((size_t)B_ * NMP_ * 2);
  bf16_t* fEb   = (bf16_t*)alloc((size_t)B_ * CH_ * 2);
  bf16_t* Woutb = (bf16_t*)alloc((size_t)NCLS_ * 2 * CH_ * 2);
  float*  bkv   = (float*)alloc(2 * CH_ * 4);
  float*  bE    = (float*)alloc(2 * CH_ * 4);
  float*  EvW   = (float*)alloc(NMP_ * 4);

  // 1) merged conversions + sf transpose
  kPrepAll<<<4620, 256, 0, stream>>>(x, Wk, Wv, WEk, WEv, bk, bv, bEk, bEv,
                                     Wout, sf, xb, Wkvb, WEb, Woutb, sfTb,
                                     bkv, bE);
  // 2) fused kv+E GEMM, split-K x4 (1408 blocks), partial planes in KVE
  gemm128<<<dim3(16, 22, ZKV_), 256, 0, stream>>>(
      xb, sfTb, B_, Wkvb, WEb, bkv, bE, CIN_,
      KVE, 2048, PS, B_ + NM_, CIN_ / ZKV_);
  // 3) merged plane-sum + normalize (knb/Eknb, EvW) + Ev transpose (Ev2b)
  kNormTr<<<1472, 256, 0, stream>>>(KVE, PS, Ww, knb, Eknb, EvW, Ev2b);
  // 4) cos GEMM, 128x64 tiles, split-K x2 (384 blocks)
  gemm_n64<0><<<dim3(NMP_ / 64, 16, ZC_), 256, 0, stream>>>(
      knb, Eknb, CH_, cosb, nullptr, NMP_, PSc, CH_ / ZC_);
  // 5) softmax chain -> wwb
  kSoftmax<<<B_, 256, 0, stream>>>(cosb, PSc, EvW, bw, wwb);
  // 6) fE GEMM, 128x64 tiles (256 blocks), relu-bf16 epilogue
  gemm_n64<1><<<dim3(CH_ / 64, 16, 1), 256, 0, stream>>>(
      wwb, Ev2b, NMP_, nullptr, fEb, CH_, 0, NMP_);
  // 7) output
  kOut<<<B_, 256, 0, stream>>>(KVE, PS, fEb, Woutb, bout, out);
}

// Round 6
// 349.301 us; speedup vs baseline: 1.0589x; 1.0589x over previous
//
#include <hip/hip_runtime.h>
#include <math.h>

#define B_    2048
#define T_    8
#define CIN_  2048
#define CH_   1024
#define M_    32
#define NCLS_ 21
#define NM_   (NCLS_*M_)   // 672
#define NMP_  768          // nm padded to 6*128
#define EPS_  1e-8f
#define ZKV_  2            // split-K planes for fused kv+E GEMM (z-sweep optimum)
#define ZC_   2            // split-K planes for cos GEMM

typedef __bf16 bf16_t;
typedef bf16_t bf16x4 __attribute__((ext_vector_type(4)));
typedef bf16_t bf16x8 __attribute__((ext_vector_type(8)));
typedef float  floatx4 __attribute__((ext_vector_type(4)));

#define GLOBAL_AS __attribute__((address_space(1)))
#define LDS_AS    __attribute__((address_space(3)))

// ---------------------------------------------------------------------------
// 128x128 bf16 MFMA GEMM, split-K over blockIdx.z:
//   C[z][M][N] partial = A[., zK..zK+Ksplit) . B^T (+ bias if z==0)
//   Partials stored as bf16 (f32 accum in AGPRs; only the plane store is
//   rounded — consumers sum the z-planes in f32).
//   m0 >= msplit switches operand set (A1,B1,bias1). Rows >= mzero -> 0.
// ---------------------------------------------------------------------------
__global__ __launch_bounds__(256) void gemm128(
    const bf16_t* __restrict__ A0, const bf16_t* __restrict__ A1, int msplit,
    const bf16_t* __restrict__ B0, const bf16_t* __restrict__ B1,
    const float* __restrict__ bias0, const float* __restrict__ bias1,
    int ld, bf16_t* __restrict__ C, int ldc, size_t strideC, int mzero, int Ksplit)
{
  __shared__ bf16_t As[128 * 64];
  __shared__ bf16_t Bs[128 * 64];
  const int tid = threadIdx.x;
  const int n0 = blockIdx.x * 128, m0 = blockIdx.y * 128;
  const int z = blockIdx.z;

  const bf16_t* A; const bf16_t* B; const float* bias; int mrow;
  if (m0 < msplit) { A = A0; B = B0; bias = bias0; mrow = m0; }
  else             { A = A1; B = B1; bias = bias1; mrow = m0 - msplit; }
  const int koff = z * Ksplit;

  const int w = tid >> 6, lane = tid & 63;
  const int srow = lane >> 3;
  const int sblk = (lane & 7) ^ srow;   // xor-swizzle folded into global addr
  const bf16_t* ga = A + (size_t)(mrow + w * 32 + srow) * ld + koff + sblk * 8;
  const bf16_t* gb = B + (size_t)(n0   + w * 32 + srow) * ld + koff + sblk * 8;

  const int wm = (w >> 1) * 64, wn = (w & 1) * 64;
  const int l15 = lane & 15, quad = lane >> 4;
  const int sx = l15 & 7;

  floatx4 acc[4][4] = {};

  for (int k0 = 0; k0 < Ksplit; k0 += 64) {
    __syncthreads();
    #pragma unroll
    for (int q = 0; q < 4; ++q) {
      __builtin_amdgcn_global_load_lds(
          (const GLOBAL_AS void*)(ga + (size_t)q * 8 * ld),
          (LDS_AS void*)(&As[(w * 4 + q) * 512]), 16, 0, 0);
      __builtin_amdgcn_global_load_lds(
          (const GLOBAL_AS void*)(gb + (size_t)q * 8 * ld),
          (LDS_AS void*)(&Bs[(w * 4 + q) * 512]), 16, 0, 0);
    }
    ga += 64; gb += 64;
    __syncthreads();
    #pragma unroll
    for (int ks = 0; ks < 2; ++ks) {
      bf16x8 af[4], bfr[4];
      #pragma unroll
      for (int i = 0; i < 4; ++i)
        af[i] = *(const bf16x8*)(&As[(wm + i * 16 + l15) * 64 + ((ks * 4 + quad) ^ sx) * 8]);
      #pragma unroll
      for (int j = 0; j < 4; ++j)
        bfr[j] = *(const bf16x8*)(&Bs[(wn + j * 16 + l15) * 64 + ((ks * 4 + quad) ^ sx) * 8]);
      #pragma unroll
      for (int i = 0; i < 4; ++i)
        #pragma unroll
        for (int j = 0; j < 4; ++j)
          acc[i][j] = __builtin_amdgcn_mfma_f32_16x16x32_bf16(af[i], bfr[j], acc[i][j], 0, 0, 0);
    }
  }

  bf16_t* Cz = C + (size_t)z * strideC;
  #pragma unroll
  for (int i = 0; i < 4; ++i) {
    const int rbase = m0 + wm + i * 16 + quad * 4;
    #pragma unroll
    for (int j = 0; j < 4; ++j) {
      const int c = n0 + wn + j * 16 + l15;
      const float badd = (bias && z == 0) ? bias[c] : 0.f;
      #pragma unroll
      for (int r = 0; r < 4; ++r) {
        const int rr = rbase + r;
        float v = acc[i][j][r] + badd;
        if (rr >= mzero) v = 0.f;
        Cz[(size_t)rr * ldc + c] = (bf16_t)v;
      }
    }
  }
}

// ---------------------------------------------------------------------------
// 128x64 bf16 MFMA GEMM, split-K over z. Stores bf16 to Cb + z*strideC.
// MODE 0: plain partial store. MODE 1: relu store (single z).
// Each wave: 32(M)x64(N).
// ---------------------------------------------------------------------------
template<int MODE>
__global__ __launch_bounds__(256) void gemm_n64(
    const bf16_t* __restrict__ A, const bf16_t* __restrict__ B, int ld,
    bf16_t* __restrict__ Cb, int ldc, size_t strideC, int Ksplit)
{
  __shared__ bf16_t As[128 * 64];
  __shared__ bf16_t Bs[64 * 64];
  const int tid = threadIdx.x;
  const int n0 = blockIdx.x * 64, m0 = blockIdx.y * 128;
  const int z = blockIdx.z;
  const int koff = z * Ksplit;

  const int w = tid >> 6, lane = tid & 63;
  const int srow = lane >> 3;
  const int sblk = (lane & 7) ^ srow;
  const bf16_t* ga = A + (size_t)(m0 + w * 32 + srow) * ld + koff + sblk * 8;
  const bf16_t* gb = B + (size_t)(n0 + w * 16 + srow) * ld + koff + sblk * 8;

  const int l15 = lane & 15, quad = lane >> 4;
  const int sx = l15 & 7;

  floatx4 acc[2][4] = {};

  for (int k0 = 0; k0 < Ksplit; k0 += 64) {
    __syncthreads();
    #pragma unroll
    for (int q = 0; q < 4; ++q)
      __builtin_amdgcn_global_load_lds(
          (const GLOBAL_AS void*)(ga + (size_t)q * 8 * ld),
          (LDS_AS void*)(&As[(w * 4 + q) * 512]), 16, 0, 0);
    #pragma unroll
    for (int q = 0; q < 2; ++q)
      __builtin_amdgcn_global_load_lds(
          (const GLOBAL_AS void*)(gb + (size_t)q * 8 * ld),
          (LDS_AS void*)(&Bs[(w * 2 + q) * 512]), 16, 0, 0);
    ga += 64; gb += 64;
    __syncthreads();
    #pragma unroll
    for (int ks = 0; ks < 2; ++ks) {
      bf16x8 af[2], bfr[4];
      #pragma unroll
      for (int i = 0; i < 2; ++i)
        af[i] = *(const bf16x8*)(&As[(w * 32 + i * 16 + l15) * 64 + ((ks * 4 + quad) ^ sx) * 8]);
      #pragma unroll
      for (int j = 0; j < 4; ++j)
        bfr[j] = *(const bf16x8*)(&Bs[(j * 16 + l15) * 64 + ((ks * 4 + quad) ^ sx) * 8]);
      #pragma unroll
      for (int i = 0; i < 2; ++i)
        #pragma unroll
        for (int j = 0; j < 4; ++j)
          acc[i][j] = __builtin_amdgcn_mfma_f32_16x16x32_bf16(af[i], bfr[j], acc[i][j], 0, 0, 0);
    }
  }

  bf16_t* Cz = Cb + (size_t)z * strideC;
  #pragma unroll
  for (int i = 0; i < 2; ++i) {
    const int rbase = m0 + w * 32 + i * 16 + quad * 4;
    #pragma unroll
    for (int j = 0; j < 4; ++j) {
      const int c = n0 + j * 16 + l15;
      #pragma unroll
      for (int r = 0; r < 4; ++r) {
        const int rr = rbase + r;
        const float v = acc[i][j][r];
        Cz[(size_t)rr * ldc + c] = (bf16_t)(MODE == 1 ? fmaxf(v, 0.f) : v);
      }
    }
  }
}

// ---------------------------------------------------------------------------
// Merged prep: f32->bf16 of x-slice / [Wk;Wv] / [WEk;WEv] / Wout, bias
// concat, and sf transpose. grid 4620 x 256.
//   blk 0..3071   : big conversions (sec = blk>>10)
//   blk 3072      : biases
//   blk 3073..3083: Wout -> bf16
//   blk 3084..4619: sf[n][c][m] -> sfTb[n*32+m][c] (pad rows zero)
// ---------------------------------------------------------------------------
__global__ __launch_bounds__(256) void kPrepAll(
    const float* __restrict__ x, const float* __restrict__ Wk,
    const float* __restrict__ Wv, const float* __restrict__ WEk,
    const float* __restrict__ WEv, const float* __restrict__ bk,
    const float* __restrict__ bv, const float* __restrict__ bEk,
    const float* __restrict__ bEv, const float* __restrict__ Wout,
    const float* __restrict__ sf,
    bf16_t* __restrict__ xb, bf16_t* __restrict__ Wkvb, bf16_t* __restrict__ WEb,
    bf16_t* __restrict__ Woutb, bf16_t* __restrict__ sfTb,
    float* __restrict__ bkv, float* __restrict__ bE)
{
  __shared__ float t[32][33];
  const int blk = blockIdx.x;
  const int tid = threadIdx.x;

  if (blk >= 3084) {   // sf transpose
    const int tt = blk - 3084;        // 0..1535
    const int nn = tt % 24;
    const int c0 = (tt / 24) * 32;
    const int cc = tid & 31, r8 = tid >> 5;
    #pragma unroll
    for (int q = 0; q < 4; ++q) {
      const int cl = r8 + q * 8;
      float v = 0.f;
      if (nn < NCLS_) v = sf[((size_t)nn * CIN_ + c0 + cl) * M_ + cc];
      t[cl][cc] = v;
    }
    __syncthreads();
    #pragma unroll
    for (int q = 0; q < 4; ++q) {
      const int ml = r8 + q * 8;
      sfTb[(size_t)(nn * 32 + ml) * CIN_ + c0 + cc] = (bf16_t)t[cc][ml];
    }
    return;
  }
  if (blk == 3072) {
    for (int i = tid; i < CH_; i += 256) {
      bkv[i] = bk[i]; bkv[CH_ + i] = bv[i];
      bE[i]  = bEk[i]; bE[CH_ + i] = bEv[i];
    }
    return;
  }
  if (blk > 3072) {    // Wout
    const size_t e0 = ((size_t)(blk - 3073) * 256 + tid) * 16;
    if (e0 < (size_t)NCLS_ * 2 * CH_) {
      #pragma unroll
      for (int q = 0; q < 4; ++q) {
        const float4 v = *(const float4*)(Wout + e0 + q * 4);
        bf16x4 o = { (bf16_t)v.x, (bf16_t)v.y, (bf16_t)v.z, (bf16_t)v.w };
        *(bf16x4*)(Woutb + e0 + q * 4) = o;
      }
    }
    return;
  }
  const int sec = blk >> 10;
  const int tt = ((blk & 1023) << 8) + tid;
  const size_t e0 = (size_t)tt * 16;
  const int row = (int)(e0 >> 11);
  const int col = (int)(e0 & 2047);
  const float* src;
  bf16_t* dst;
  if (sec == 0) {
    src = x + (size_t)row * (T_ * CIN_) + (size_t)(T_ - 1) * CIN_ + col;
    dst = xb + e0;
  } else if (sec == 1) {
    src = (row < CH_ ? Wk + (size_t)row * CIN_ : Wv + (size_t)(row - CH_) * CIN_) + col;
    dst = Wkvb + e0;
  } else {
    src = (row < CH_ ? WEk + (size_t)row * CIN_ : WEv + (size_t)(row - CH_) * CIN_) + col;
    dst = WEb + e0;
  }
  #pragma unroll
  for (int q = 0; q < 4; ++q) {
    const float4 v = *(const float4*)(src + q * 4);
    bf16x4 o = { (bf16_t)v.x, (bf16_t)v.y, (bf16_t)v.z, (bf16_t)v.w };
    *(bf16x4*)(dst + q * 4) = o;
  }
}

// ---------------------------------------------------------------------------
// Merged norm + Ev transpose (KVE = sum of ZKV_ bf16 planes, stride PS):
//   blk 0..703   : 4 rows each (wave per row). Normalize cols 0..1023 of row
//                  r -> knb (r<2048) or Eknb; r>=2048 also EvW = dot(Ev, Ww).
//   blk 704..1471: Ev2b[o][nm] = sum_z KVE_z[2048+nm][1024+o] (bf16), 32x32.
// grid 1472 x 256.
// ---------------------------------------------------------------------------
__global__ __launch_bounds__(256) void kNormTr(
    const bf16_t* __restrict__ KVE, size_t PS, const float* __restrict__ Ww,
    bf16_t* __restrict__ knb, bf16_t* __restrict__ Eknb, float* __restrict__ EvW,
    bf16_t* __restrict__ Ev2b)
{
  __shared__ float t[32][33];
  const int blk = blockIdx.x;
  const int tid = threadIdx.x;

  if (blk < 704) {
    const int r = blk * 4 + (tid >> 6);
    const int lane = tid & 63;
    const bf16_t* row = KVE + (size_t)r * 2048;
    float vals[16];
    float ss = 0.f;
    #pragma unroll
    for (int i = 0; i < 16; ++i) {
      const int o = lane + i * 64;
      float v = (float)row[o];
      #pragma unroll
      for (int z = 1; z < ZKV_; ++z) v += (float)row[(size_t)z * PS + o];
      vals[i] = v;
      ss += v * v;
    }
    for (int off = 32; off; off >>= 1) ss += __shfl_xor(ss, off);
    const float inv = 1.f / fmaxf(sqrtf(ss), EPS_);
    bf16_t* dst = (r < B_) ? knb + (size_t)r * CH_ : Eknb + (size_t)(r - B_) * CH_;
    #pragma unroll
    for (int i = 0; i < 16; ++i) dst[lane + i * 64] = (bf16_t)(vals[i] * inv);
    if (r >= B_) {
      float dd = 0.f;
      for (int o = lane; o < CH_; o += 64) {
        float v = (float)row[CH_ + o];
        #pragma unroll
        for (int z = 1; z < ZKV_; ++z) v += (float)row[(size_t)z * PS + CH_ + o];
        dd += v * Ww[o];
      }
      for (int off = 32; off; off >>= 1) dd += __shfl_xor(dd, off);
      if (lane == 0) EvW[r - B_] = dd;
    }
    return;
  }
  const int tt = blk - 704;           // 0..767
  const int nm0 = (tt % 24) * 32;
  const int o0 = (tt / 24) * 32;
  const int cc = tid & 31, r8 = tid >> 5;
  #pragma unroll
  for (int q = 0; q < 4; ++q) {
    const int r = r8 + q * 8;
    const size_t idx = (size_t)(B_ + nm0 + r) * 2048 + CH_ + o0 + cc;
    float v = (float)KVE[idx];
    #pragma unroll
    for (int z = 1; z < ZKV_; ++z) v += (float)KVE[(size_t)z * PS + idx];
    t[r][cc] = v;
  }
  __syncthreads();
  #pragma unroll
  for (int q = 0; q < 4; ++q) {
    const int r = r8 + q * 8;
    Ev2b[(size_t)(o0 + r) * NMP_ + nm0 + cc] = (bf16_t)t[cc][r];
  }
}

// ---------------------------------------------------------------------------
// Softmax chain per b, summing ZC_ bf16 cos planes (stride PSc). -> wwb bf16.
// ---------------------------------------------------------------------------
__global__ __launch_bounds__(256) void kSoftmax(
    const bf16_t* __restrict__ cosb, size_t PSc,
    const float* __restrict__ EvW, const float* __restrict__ bw,
    bf16_t* __restrict__ wwb)
{
  const int b = blockIdx.x;
  const int tid = threadIdx.x;
  __shared__ float sc[NM_];
  __shared__ float sl[NCLS_];
  for (int i = tid; i < NM_; i += 256) {
    float v = (float)cosb[(size_t)b * NMP_ + i];
    #pragma unroll
    for (int z = 1; z < ZC_; ++z) v += (float)cosb[(size_t)z * PSc + (size_t)b * NMP_ + i];
    sc[i] = v;
  }
  __syncthreads();
  if (tid < NCLS_) {
    const int base = tid * M_;
    float mx = -1e30f;
    for (int m = 0; m < M_; ++m) mx = fmaxf(mx, sc[base + m]);
    float s = 0.f;
    for (int m = 0; m < M_; ++m) {
      const float e = __expf(sc[base + m] - mx);
      sc[base + m] = e;
      s += e;
    }
    const float inv = 1.f / s;
    float lg = 0.f;
    for (int m = 0; m < M_; ++m) {
      const float w = sc[base + m] * inv;
      sc[base + m] = w;
      lg += w * EvW[base + m];
    }
    sl[tid] = lg + bw[0];
  }
  __syncthreads();
  if (tid == 0) {
    float mx = -1e30f;
    for (int n = 0; n < NCLS_; ++n) mx = fmaxf(mx, sl[n]);
    float s = 0.f;
    for (int n = 0; n < NCLS_; ++n) { const float e = __expf(sl[n] - mx); sl[n] = e; s += e; }
    const float inv = 1.f / s;
    for (int n = 0; n < NCLS_; ++n) sl[n] *= inv;
  }
  __syncthreads();
  for (int i = tid; i < NMP_; i += 256) {
    const float v = (i < NM_) ? sc[i] * sl[i >> 5] : 0.f;
    wwb[(size_t)b * NMP_ + i] = (bf16_t)v;
  }
}

// ---------------------------------------------------------------------------
// out[b,n] = bout[n] + sum_j relu(h[j]) * Woutb[n,j]; h = [sum_z v_z, fEb]
// ---------------------------------------------------------------------------
__global__ __launch_bounds__(256) void kOut(
    const bf16_t* __restrict__ KVE, size_t PS,
    const bf16_t* __restrict__ fEb, const bf16_t* __restrict__ Woutb,
    const float* __restrict__ bout, float* __restrict__ out)
{
  const int b = blockIdx.x;
  const int tid = threadIdx.x;
  __shared__ float h[2 * CH_];
  for (int j = tid; j < CH_; j += 256) {
    const size_t idx = (size_t)b * 2048 + CH_ + j;
    float v = (float)KVE[idx];
    #pragma unroll
    for (int z = 1; z < ZKV_; ++z) v += (float)KVE[(size_t)z * PS + idx];
    h[j] = fmaxf(v, 0.f);
  }
  for (int j = tid; j < CH_; j += 256)
    h[CH_ + j] = (float)fEb[(size_t)b * CH_ + j];
  __syncthreads();
  const int wave = tid >> 6, lane = tid & 63;
  for (int n = wave; n < NCLS_; n += 4) {
    const bf16_t* wr = Woutb + (size_t)n * (2 * CH_);
    float s = 0.f;
    for (int j = lane; j < 2 * CH_; j += 64) s += h[j] * (float)wr[j];
    for (int off = 32; off; off >>= 1) s += __shfl_xor(s, off);
    if (lane == 0) out[(size_t)b * NCLS_ + n] = s + bout[n];
  }
}

// ---------------------------------------------------------------------------
extern "C" void kernel_launch(void* const* d_in, const int* in_sizes, int n_in,
                              void* d_out, int out_size, void* d_ws, size_t ws_size,
                              hipStream_t stream)
{
  const float* x    = (const float*)d_in[0];
  const float* sf   = (const float*)d_in[1];
  const float* Wk   = (const float*)d_in[2];
  const float* bk   = (const float*)d_in[3];
  const float* Wv   = (const float*)d_in[4];
  const float* bv   = (const float*)d_in[5];
  const float* WEk  = (const float*)d_in[6];
  const float* bEk  = (const float*)d_in[7];
  const float* WEv  = (const float*)d_in[8];
  const float* bEv  = (const float*)d_in[9];
  const float* Ww   = (const float*)d_in[10];
  const float* bw   = (const float*)d_in[11];
  const float* Wout = (const float*)d_in[12];
  const float* bout = (const float*)d_in[13];
  float* out = (float*)d_out;

  char* ws = (char*)d_ws;
  size_t off = 0;
  auto alloc = [&](size_t bytes) { char* p = ws + off; off += (bytes + 255) & ~(size_t)255; return p; };
  const size_t PS  = (size_t)2816 * 2048;               // KVE plane elems
  const size_t PSc = (size_t)B_ * NMP_;                 // cos plane elems
  bf16_t* KVE   = (bf16_t*)alloc(PS * ZKV_ * 2);        // 23.07 MB (bf16 partials)
  bf16_t* xb    = (bf16_t*)alloc((size_t)2048 * 2048 * 2);
  bf16_t* Wkvb  = (bf16_t*)alloc((size_t)2048 * 2048 * 2);
  bf16_t* WEb   = (bf16_t*)alloc((size_t)2048 * 2048 * 2);
  bf16_t* sfTb  = (bf16_t*)alloc((size_t)NMP_ * 2048 * 2);
  bf16_t* knb   = (bf16_t*)alloc((size_t)B_ * CH_ * 2);
  bf16_t* Eknb  = (bf16_t*)alloc((size_t)NMP_ * CH_ * 2);
  bf16_t* Ev2b  = (bf16_t*)alloc((size_t)CH_ * NMP_ * 2);
  bf16_t* cosb  = (bf16_t*)alloc(PSc * ZC_ * 2);        // bf16 partials
  bf16_t* wwb   = (bf16_t*)alloc((size_t)B_ * NMP_ * 2);
  bf16_t* fEb   = (bf16_t*)alloc((size_t)B_ * CH_ * 2);
  bf16_t* Woutb = (bf16_t*)alloc((size_t)NCLS_ * 2 * CH_ * 2);
  float*  bkv   = (float*)alloc(2 * CH_ * 4);
  float*  bE    = (float*)alloc(2 * CH_ * 4);
  float*  EvW   = (float*)alloc(NMP_ * 4);

  // 1) merged conversions + sf transpose
  kPrepAll<<<4620, 256, 0, stream>>>(x, Wk, Wv, WEk, WEv, bk, bv, bEk, bEv,
                                     Wout, sf, xb, Wkvb, WEb, Woutb, sfTb,
                                     bkv, bE);
  // 2) fused kv+E GEMM, split-K x2 (704 blocks), bf16 partial planes
  gemm128<<<dim3(16, 22, ZKV_), 256, 0, stream>>>(
      xb, sfTb, B_, Wkvb, WEb, bkv, bE, CIN_,
      KVE, 2048, PS, B_ + NM_, CIN_ / ZKV_);
  // 3) merged plane-sum + normalize (knb/Eknb, EvW) + Ev transpose (Ev2b)
  kNormTr<<<1472, 256, 0, stream>>>(KVE, PS, Ww, knb, Eknb, EvW, Ev2b);
  // 4) cos GEMM, 128x64 tiles, split-K x2 (384 blocks), bf16 partials
  gemm_n64<0><<<dim3(NMP_ / 64, 16, ZC_), 256, 0, stream>>>(
      knb, Eknb, CH_, cosb, NMP_, PSc, CH_ / ZC_);
  // 5) softmax chain -> wwb
  kSoftmax<<<B_, 256, 0, stream>>>(cosb, PSc, EvW, bw, wwb);
  // 6) fE GEMM, 128x64 tiles (256 blocks), relu-bf16 epilogue
  gemm_n64<1><<<dim3(CH_ / 64, 16, 1), 256, 0, stream>>>(
      wwb, Ev2b, NMP_, fEb, CH_, 0, NMP_);
  // 7) output
  kOut<<<B_, 256, 0, stream>>>(KVE, PS, fEb, Woutb, bout, out);
}

// Round 7
// 312.332 us; speedup vs baseline: 1.1842x; 1.1184x over previous
//
#include <hip/hip_runtime.h>
#include <math.h>

#define B_    2048
#define T_    8
#define CIN_  2048
#define CH_   1024
#define M_    32
#define NCLS_ 21
#define NM_   (NCLS_*M_)   // 672
#define NMP_  768          // nm padded to 6*128
#define EPS_  1e-8f
#define ZKV_  2            // split-K planes for fused kv+E GEMM (z-sweep optimum)
#define ZC_   2            // split-K planes for cos GEMM

typedef __bf16 bf16_t;
typedef bf16_t bf16x4 __attribute__((ext_vector_type(4)));
typedef bf16_t bf16x8 __attribute__((ext_vector_type(8)));
typedef float  floatx4 __attribute__((ext_vector_type(4)));

#define GLOBAL_AS __attribute__((address_space(1)))
#define LDS_AS    __attribute__((address_space(3)))

// ---------------------------------------------------------------------------
// 128x128 bf16 MFMA GEMM, split-K over blockIdx.z (bf16 partial planes):
//   C[z][M][N] = A[., zK..zK+Ksplit) . B^T (+ bias if z==0)
//   m0 >= msplit switches operand set (A1,B1,bias1). Rows >= mzero -> 0.
// ---------------------------------------------------------------------------
__global__ __launch_bounds__(256) void gemm128(
    const bf16_t* __restrict__ A0, const bf16_t* __restrict__ A1, int msplit,
    const bf16_t* __restrict__ B0, const bf16_t* __restrict__ B1,
    const float* __restrict__ bias0, const float* __restrict__ bias1,
    int ld, bf16_t* __restrict__ C, int ldc, size_t strideC, int mzero, int Ksplit)
{
  __shared__ bf16_t As[128 * 64];
  __shared__ bf16_t Bs[128 * 64];
  const int tid = threadIdx.x;
  const int n0 = blockIdx.x * 128, m0 = blockIdx.y * 128;
  const int z = blockIdx.z;

  const bf16_t* A; const bf16_t* B; const float* bias; int mrow;
  if (m0 < msplit) { A = A0; B = B0; bias = bias0; mrow = m0; }
  else             { A = A1; B = B1; bias = bias1; mrow = m0 - msplit; }
  const int koff = z * Ksplit;

  const int w = tid >> 6, lane = tid & 63;
  const int srow = lane >> 3;
  const int sblk = (lane & 7) ^ srow;   // xor-swizzle folded into global addr
  const bf16_t* ga = A + (size_t)(mrow + w * 32 + srow) * ld + koff + sblk * 8;
  const bf16_t* gb = B + (size_t)(n0   + w * 32 + srow) * ld + koff + sblk * 8;

  const int wm = (w >> 1) * 64, wn = (w & 1) * 64;
  const int l15 = lane & 15, quad = lane >> 4;
  const int sx = l15 & 7;

  floatx4 acc[4][4] = {};

  for (int k0 = 0; k0 < Ksplit; k0 += 64) {
    __syncthreads();
    #pragma unroll
    for (int q = 0; q < 4; ++q) {
      __builtin_amdgcn_global_load_lds(
          (const GLOBAL_AS void*)(ga + (size_t)q * 8 * ld),
          (LDS_AS void*)(&As[(w * 4 + q) * 512]), 16, 0, 0);
      __builtin_amdgcn_global_load_lds(
          (const GLOBAL_AS void*)(gb + (size_t)q * 8 * ld),
          (LDS_AS void*)(&Bs[(w * 4 + q) * 512]), 16, 0, 0);
    }
    ga += 64; gb += 64;
    __syncthreads();
    #pragma unroll
    for (int ks = 0; ks < 2; ++ks) {
      bf16x8 af[4], bfr[4];
      #pragma unroll
      for (int i = 0; i < 4; ++i)
        af[i] = *(const bf16x8*)(&As[(wm + i * 16 + l15) * 64 + ((ks * 4 + quad) ^ sx) * 8]);
      #pragma unroll
      for (int j = 0; j < 4; ++j)
        bfr[j] = *(const bf16x8*)(&Bs[(wn + j * 16 + l15) * 64 + ((ks * 4 + quad) ^ sx) * 8]);
      #pragma unroll
      for (int i = 0; i < 4; ++i)
        #pragma unroll
        for (int j = 0; j < 4; ++j)
          acc[i][j] = __builtin_amdgcn_mfma_f32_16x16x32_bf16(af[i], bfr[j], acc[i][j], 0, 0, 0);
    }
  }

  bf16_t* Cz = C + (size_t)z * strideC;
  #pragma unroll
  for (int i = 0; i < 4; ++i) {
    const int rbase = m0 + wm + i * 16 + quad * 4;
    #pragma unroll
    for (int j = 0; j < 4; ++j) {
      const int c = n0 + wn + j * 16 + l15;
      const float badd = (bias && z == 0) ? bias[c] : 0.f;
      #pragma unroll
      for (int r = 0; r < 4; ++r) {
        const int rr = rbase + r;
        float v = acc[i][j][r] + badd;
        if (rr >= mzero) v = 0.f;
        Cz[(size_t)rr * ldc + c] = (bf16_t)v;
      }
    }
  }
}

// ---------------------------------------------------------------------------
// 128x64 bf16 MFMA GEMM, split-K over z. Stores bf16 to Cb + z*strideC.
// MODE 0: plain partial store. MODE 1: relu store (single z; used to write
// the fE half of hb with ldc=2048). Each wave: 32(M)x64(N).
// ---------------------------------------------------------------------------
template<int MODE>
__global__ __launch_bounds__(256) void gemm_n64(
    const bf16_t* __restrict__ A, const bf16_t* __restrict__ B, int ld,
    bf16_t* __restrict__ Cb, int ldc, size_t strideC, int Ksplit)
{
  __shared__ bf16_t As[128 * 64];
  __shared__ bf16_t Bs[64 * 64];
  const int tid = threadIdx.x;
  const int n0 = blockIdx.x * 64, m0 = blockIdx.y * 128;
  const int z = blockIdx.z;
  const int koff = z * Ksplit;

  const int w = tid >> 6, lane = tid & 63;
  const int srow = lane >> 3;
  const int sblk = (lane & 7) ^ srow;
  const bf16_t* ga = A + (size_t)(m0 + w * 32 + srow) * ld + koff + sblk * 8;
  const bf16_t* gb = B + (size_t)(n0 + w * 16 + srow) * ld + koff + sblk * 8;

  const int l15 = lane & 15, quad = lane >> 4;
  const int sx = l15 & 7;

  floatx4 acc[2][4] = {};

  for (int k0 = 0; k0 < Ksplit; k0 += 64) {
    __syncthreads();
    #pragma unroll
    for (int q = 0; q < 4; ++q)
      __builtin_amdgcn_global_load_lds(
          (const GLOBAL_AS void*)(ga + (size_t)q * 8 * ld),
          (LDS_AS void*)(&As[(w * 4 + q) * 512]), 16, 0, 0);
    #pragma unroll
    for (int q = 0; q < 2; ++q)
      __builtin_amdgcn_global_load_lds(
          (const GLOBAL_AS void*)(gb + (size_t)q * 8 * ld),
          (LDS_AS void*)(&Bs[(w * 2 + q) * 512]), 16, 0, 0);
    ga += 64; gb += 64;
    __syncthreads();
    #pragma unroll
    for (int ks = 0; ks < 2; ++ks) {
      bf16x8 af[2], bfr[4];
      #pragma unroll
      for (int i = 0; i < 2; ++i)
        af[i] = *(const bf16x8*)(&As[(w * 32 + i * 16 + l15) * 64 + ((ks * 4 + quad) ^ sx) * 8]);
      #pragma unroll
      for (int j = 0; j < 4; ++j)
        bfr[j] = *(const bf16x8*)(&Bs[(j * 16 + l15) * 64 + ((ks * 4 + quad) ^ sx) * 8]);
      #pragma unroll
      for (int i = 0; i < 2; ++i)
        #pragma unroll
        for (int j = 0; j < 4; ++j)
          acc[i][j] = __builtin_amdgcn_mfma_f32_16x16x32_bf16(af[i], bfr[j], acc[i][j], 0, 0, 0);
    }
  }

  bf16_t* Cz = Cb + (size_t)z * strideC;
  #pragma unroll
  for (int i = 0; i < 2; ++i) {
    const int rbase = m0 + w * 32 + i * 16 + quad * 4;
    #pragma unroll
    for (int j = 0; j < 4; ++j) {
      const int c = n0 + j * 16 + l15;
      #pragma unroll
      for (int r = 0; r < 4; ++r) {
        const int rr = rbase + r;
        const float v = acc[i][j][r];
        Cz[(size_t)rr * ldc + c] = (bf16_t)(MODE == 1 ? fmaxf(v, 0.f) : v);
      }
    }
  }
}

// ---------------------------------------------------------------------------
// Merged prep: f32->bf16 of x-slice / [Wk;Wv] / [WEk;WEv] / Wout, bias
// concat, and sf transpose. grid 4620 x 256.
// ---------------------------------------------------------------------------
__global__ __launch_bounds__(256) void kPrepAll(
    const float* __restrict__ x, const float* __restrict__ Wk,
    const float* __restrict__ Wv, const float* __restrict__ WEk,
    const float* __restrict__ WEv, const float* __restrict__ bk,
    const float* __restrict__ bv, const float* __restrict__ bEk,
    const float* __restrict__ bEv, const float* __restrict__ Wout,
    const float* __restrict__ sf,
    bf16_t* __restrict__ xb, bf16_t* __restrict__ Wkvb, bf16_t* __restrict__ WEb,
    bf16_t* __restrict__ Woutb, bf16_t* __restrict__ sfTb,
    float* __restrict__ bkv, float* __restrict__ bE)
{
  __shared__ float t[32][33];
  const int blk = blockIdx.x;
  const int tid = threadIdx.x;

  if (blk >= 3084) {   // sf transpose
    const int tt = blk - 3084;        // 0..1535
    const int nn = tt % 24;
    const int c0 = (tt / 24) * 32;
    const int cc = tid & 31, r8 = tid >> 5;
    #pragma unroll
    for (int q = 0; q < 4; ++q) {
      const int cl = r8 + q * 8;
      float v = 0.f;
      if (nn < NCLS_) v = sf[((size_t)nn * CIN_ + c0 + cl) * M_ + cc];
      t[cl][cc] = v;
    }
    __syncthreads();
    #pragma unroll
    for (int q = 0; q < 4; ++q) {
      const int ml = r8 + q * 8;
      sfTb[(size_t)(nn * 32 + ml) * CIN_ + c0 + cc] = (bf16_t)t[cc][ml];
    }
    return;
  }
  if (blk == 3072) {
    for (int i = tid; i < CH_; i += 256) {
      bkv[i] = bk[i]; bkv[CH_ + i] = bv[i];
      bE[i]  = bEk[i]; bE[CH_ + i] = bEv[i];
    }
    return;
  }
  if (blk > 3072) {    // Wout
    const size_t e0 = ((size_t)(blk - 3073) * 256 + tid) * 16;
    if (e0 < (size_t)NCLS_ * 2 * CH_) {
      #pragma unroll
      for (int q = 0; q < 4; ++q) {
        const float4 v = *(const float4*)(Wout + e0 + q * 4);
        bf16x4 o = { (bf16_t)v.x, (bf16_t)v.y, (bf16_t)v.z, (bf16_t)v.w };
        *(bf16x4*)(Woutb + e0 + q * 4) = o;
      }
    }
    return;
  }
  const int sec = blk >> 10;
  const int tt = ((blk & 1023) << 8) + tid;
  const size_t e0 = (size_t)tt * 16;
  const int row = (int)(e0 >> 11);
  const int col = (int)(e0 & 2047);
  const float* src;
  bf16_t* dst;
  if (sec == 0) {
    src = x + (size_t)row * (T_ * CIN_) + (size_t)(T_ - 1) * CIN_ + col;
    dst = xb + e0;
  } else if (sec == 1) {
    src = (row < CH_ ? Wk + (size_t)row * CIN_ : Wv + (size_t)(row - CH_) * CIN_) + col;
    dst = Wkvb + e0;
  } else {
    src = (row < CH_ ? WEk + (size_t)row * CIN_ : WEv + (size_t)(row - CH_) * CIN_) + col;
    dst = WEb + e0;
  }
  #pragma unroll
  for (int q = 0; q < 4; ++q) {
    const float4 v = *(const float4*)(src + q * 4);
    bf16x4 o = { (bf16_t)v.x, (bf16_t)v.y, (bf16_t)v.z, (bf16_t)v.w };
    *(bf16x4*)(dst + q * 4) = o;
  }
}

// ---------------------------------------------------------------------------
// Merged norm + h-build + Ev transpose (KVE = sum of ZKV_ bf16 planes):
//   blk 0..703   : 4 rows each (wave per row). Normalize cols 0..1023 of row
//                  r -> knb (r<2048) or Eknb; r<2048 also writes
//                  hb[r][0..1023] = relu(v); r>=2048 also EvW = dot(Ev, Ww).
//   blk 704..1471: Ev2b[o][nm] = sum_z KVE_z[2048+nm][1024+o] (bf16), 32x32.
// grid 1472 x 256.
// ---------------------------------------------------------------------------
__global__ __launch_bounds__(256) void kNormTr(
    const bf16_t* __restrict__ KVE, size_t PS, const float* __restrict__ Ww,
    bf16_t* __restrict__ knb, bf16_t* __restrict__ Eknb, float* __restrict__ EvW,
    bf16_t* __restrict__ Ev2b, bf16_t* __restrict__ hb)
{
  __shared__ float t[32][33];
  const int blk = blockIdx.x;
  const int tid = threadIdx.x;

  if (blk < 704) {
    const int r = blk * 4 + (tid >> 6);
    const int lane = tid & 63;
    const bf16_t* row = KVE + (size_t)r * 2048;
    float vals[16];
    float ss = 0.f;
    #pragma unroll
    for (int i = 0; i < 16; ++i) {
      const int o = lane + i * 64;
      float v = (float)row[o];
      #pragma unroll
      for (int z = 1; z < ZKV_; ++z) v += (float)row[(size_t)z * PS + o];
      vals[i] = v;
      ss += v * v;
    }
    for (int off = 32; off; off >>= 1) ss += __shfl_xor(ss, off);
    const float inv = 1.f / fmaxf(sqrtf(ss), EPS_);
    bf16_t* dst = (r < B_) ? knb + (size_t)r * CH_ : Eknb + (size_t)(r - B_) * CH_;
    #pragma unroll
    for (int i = 0; i < 16; ++i) dst[lane + i * 64] = (bf16_t)(vals[i] * inv);
    if (r < B_) {
      // h first half: relu(v) = relu(sum_z KVE_z[r][1024+o])
      #pragma unroll
      for (int i = 0; i < 16; ++i) {
        const int o = CH_ + lane + i * 64;
        float v = (float)row[o];
        #pragma unroll
        for (int z = 1; z < ZKV_; ++z) v += (float)row[(size_t)z * PS + o];
        hb[(size_t)r * 2048 + lane + i * 64] = (bf16_t)fmaxf(v, 0.f);
      }
    } else {
      float dd = 0.f;
      for (int o = lane; o < CH_; o += 64) {
        float v = (float)row[CH_ + o];
        #pragma unroll
        for (int z = 1; z < ZKV_; ++z) v += (float)row[(size_t)z * PS + CH_ + o];
        dd += v * Ww[o];
      }
      for (int off = 32; off; off >>= 1) dd += __shfl_xor(dd, off);
      if (lane == 0) EvW[r - B_] = dd;
    }
    return;
  }
  const int tt = blk - 704;           // 0..767
  const int nm0 = (tt % 24) * 32;
  const int o0 = (tt / 24) * 32;
  const int cc = tid & 31, r8 = tid >> 5;
  #pragma unroll
  for (int q = 0; q < 4; ++q) {
    const int r = r8 + q * 8;
    const size_t idx = (size_t)(B_ + nm0 + r) * 2048 + CH_ + o0 + cc;
    float v = (float)KVE[idx];
    #pragma unroll
    for (int z = 1; z < ZKV_; ++z) v += (float)KVE[(size_t)z * PS + idx];
    t[r][cc] = v;
  }
  __syncthreads();
  #pragma unroll
  for (int q = 0; q < 4; ++q) {
    const int r = r8 + q * 8;
    Ev2b[(size_t)(o0 + r) * NMP_ + nm0 + cc] = (bf16_t)t[cc][r];
  }
}

// ---------------------------------------------------------------------------
// Softmax chain per b, summing ZC_ bf16 cos planes (stride PSc). -> wwb bf16.
// ---------------------------------------------------------------------------
__global__ __launch_bounds__(256) void kSoftmax(
    const bf16_t* __restrict__ cosb, size_t PSc,
    const float* __restrict__ EvW, const float* __restrict__ bw,
    bf16_t* __restrict__ wwb)
{
  const int b = blockIdx.x;
  const int tid = threadIdx.x;
  __shared__ float sc[NM_];
  __shared__ float sl[NCLS_];
  for (int i = tid; i < NM_; i += 256) {
    float v = (float)cosb[(size_t)b * NMP_ + i];
    #pragma unroll
    for (int z = 1; z < ZC_; ++z) v += (float)cosb[(size_t)z * PSc + (size_t)b * NMP_ + i];
    sc[i] = v;
  }
  __syncthreads();
  if (tid < NCLS_) {
    const int base = tid * M_;
    float mx = -1e30f;
    for (int m = 0; m < M_; ++m) mx = fmaxf(mx, sc[base + m]);
    float s = 0.f;
    for (int m = 0; m < M_; ++m) {
      const float e = __expf(sc[base + m] - mx);
      sc[base + m] = e;
      s += e;
    }
    const float inv = 1.f / s;
    float lg = 0.f;
    for (int m = 0; m < M_; ++m) {
      const float w = sc[base + m] * inv;
      sc[base + m] = w;
      lg += w * EvW[base + m];
    }
    sl[tid] = lg + bw[0];
  }
  __syncthreads();
  if (tid == 0) {
    float mx = -1e30f;
    for (int n = 0; n < NCLS_; ++n) mx = fmaxf(mx, sl[n]);
    float s = 0.f;
    for (int n = 0; n < NCLS_; ++n) { const float e = __expf(sl[n] - mx); sl[n] = e; s += e; }
    const float inv = 1.f / s;
    for (int n = 0; n < NCLS_; ++n) sl[n] *= inv;
  }
  __syncthreads();
  for (int i = tid; i < NMP_; i += 256) {
    const float v = (i < NM_) ? sc[i] * sl[i >> 5] : 0.f;
    wwb[(size_t)b * NMP_ + i] = (bf16_t)v;
  }
}

// ---------------------------------------------------------------------------
// out[b,n] = bout[n] + sum_j hb[b][j] * Woutb[n,j].  hb already relu'd.
// 256 blocks x 8 rows; 8 h-rows staged in LDS (32 KB); each wave streams
// Wout rows n = w, w+4, ... once per block (L2 traffic 176 -> 22 MB vs R5).
// ---------------------------------------------------------------------------
__global__ __launch_bounds__(256) void kOutW(
    const bf16_t* __restrict__ hb, const bf16_t* __restrict__ Woutb,
    const float* __restrict__ bout, float* __restrict__ out)
{
  __shared__ bf16_t hs[8][2048];
  const int b0 = blockIdx.x * 8;
  const int tid = threadIdx.x;
  #pragma unroll
  for (int q = 0; q < 8; ++q) {
    const int idx = q * 256 + tid;        // 0..2047
    const int row = idx >> 8;
    const int col = (idx & 255) * 8;
    *(bf16x8*)&hs[row][col] = *(const bf16x8*)&hb[(size_t)(b0 + row) * 2048 + col];
  }
  __syncthreads();
  const int w = tid >> 6, lane = tid & 63;
  for (int n = w; n < NCLS_; n += 4) {
    const bf16_t* wr = Woutb + (size_t)n * 2048;
    float a[8] = {};
    #pragma unroll
    for (int q = 0; q < 4; ++q) {
      const int k0 = q * 512 + lane * 8;
      const bf16x8 wv = *(const bf16x8*)&wr[k0];
      #pragma unroll
      for (int r = 0; r < 8; ++r) {
        const bf16x8 hv = *(const bf16x8*)&hs[r][k0];
        float s = 0.f;
        #pragma unroll
        for (int e = 0; e < 8; ++e) s += (float)hv[e] * (float)wv[e];
        a[r] += s;
      }
    }
    #pragma unroll
    for (int r = 0; r < 8; ++r) {
      float s = a[r];
      for (int off = 32; off; off >>= 1) s += __shfl_xor(s, off);
      if (lane == 0) out[(size_t)(b0 + r) * NCLS_ + n] = s + bout[n];
    }
  }
}

// ---------------------------------------------------------------------------
extern "C" void kernel_launch(void* const* d_in, const int* in_sizes, int n_in,
                              void* d_out, int out_size, void* d_ws, size_t ws_size,
                              hipStream_t stream)
{
  const float* x    = (const float*)d_in[0];
  const float* sf   = (const float*)d_in[1];
  const float* Wk   = (const float*)d_in[2];
  const float* bk   = (const float*)d_in[3];
  const float* Wv   = (const float*)d_in[4];
  const float* bv   = (const float*)d_in[5];
  const float* WEk  = (const float*)d_in[6];
  const float* bEk  = (const float*)d_in[7];
  const float* WEv  = (const float*)d_in[8];
  const float* bEv  = (const float*)d_in[9];
  const float* Ww   = (const float*)d_in[10];
  const float* bw   = (const float*)d_in[11];
  const float* Wout = (const float*)d_in[12];
  const float* bout = (const float*)d_in[13];
  float* out = (float*)d_out;

  char* ws = (char*)d_ws;
  size_t off = 0;
  auto alloc = [&](size_t bytes) { char* p = ws + off; off += (bytes + 255) & ~(size_t)255; return p; };
  const size_t PS  = (size_t)2816 * 2048;               // KVE plane elems
  const size_t PSc = (size_t)B_ * NMP_;                 // cos plane elems
  bf16_t* KVE   = (bf16_t*)alloc(PS * ZKV_ * 2);        // 23.07 MB (bf16 partials)
  bf16_t* xb    = (bf16_t*)alloc((size_t)2048 * 2048 * 2);
  bf16_t* Wkvb  = (bf16_t*)alloc((size_t)2048 * 2048 * 2);
  bf16_t* WEb   = (bf16_t*)alloc((size_t)2048 * 2048 * 2);
  bf16_t* sfTb  = (bf16_t*)alloc((size_t)NMP_ * 2048 * 2);
  bf16_t* knb   = (bf16_t*)alloc((size_t)B_ * CH_ * 2);
  bf16_t* Eknb  = (bf16_t*)alloc((size_t)NMP_ * CH_ * 2);
  bf16_t* Ev2b  = (bf16_t*)alloc((size_t)CH_ * NMP_ * 2);
  bf16_t* cosb  = (bf16_t*)alloc(PSc * ZC_ * 2);        // bf16 partials
  bf16_t* wwb   = (bf16_t*)alloc((size_t)B_ * NMP_ * 2);
  bf16_t* hb    = (bf16_t*)alloc((size_t)B_ * 2048 * 2); // h = [relu(v), relu(fE)]
  bf16_t* Woutb = (bf16_t*)alloc((size_t)NCLS_ * 2 * CH_ * 2);
  float*  bkv   = (float*)alloc(2 * CH_ * 4);
  float*  bE    = (float*)alloc(2 * CH_ * 4);
  float*  EvW   = (float*)alloc(NMP_ * 4);

  // 1) merged conversions + sf transpose
  kPrepAll<<<4620, 256, 0, stream>>>(x, Wk, Wv, WEk, WEv, bk, bv, bEk, bEv,
                                     Wout, sf, xb, Wkvb, WEb, Woutb, sfTb,
                                     bkv, bE);
  // 2) fused kv+E GEMM, split-K x2 (704 blocks), bf16 partial planes
  gemm128<<<dim3(16, 22, ZKV_), 256, 0, stream>>>(
      xb, sfTb, B_, Wkvb, WEb, bkv, bE, CIN_,
      KVE, 2048, PS, B_ + NM_, CIN_ / ZKV_);
  // 3) plane-sum + normalize (knb/Eknb, EvW) + relu(v)->hb + Ev transpose
  kNormTr<<<1472, 256, 0, stream>>>(KVE, PS, Ww, knb, Eknb, EvW, Ev2b, hb);
  // 4) cos GEMM, 128x64 tiles, split-K x2 (384 blocks), bf16 partials
  gemm_n64<0><<<dim3(NMP_ / 64, 16, ZC_), 256, 0, stream>>>(
      knb, Eknb, CH_, cosb, NMP_, PSc, CH_ / ZC_);
  // 5) softmax chain -> wwb
  kSoftmax<<<B_, 256, 0, stream>>>(cosb, PSc, EvW, bw, wwb);
  // 6) fE GEMM, 128x64 tiles (256 blocks), relu epilogue -> hb[:,1024:2048]
  gemm_n64<1><<<dim3(CH_ / 64, 16, 1), 256, 0, stream>>>(
      wwb, Ev2b, NMP_, hb + CH_, 2048, 0, NMP_);
  // 7) output GEMV from staged h
  kOutW<<<B_ / 8, 256, 0, stream>>>(hb, Woutb, bout, out);
}